// Round 1
// baseline (2237.668 us; speedup 1.0000x reference)
//
#include <hip/hip_runtime.h>

#define B_ 4
#define S_ 1024
#define D_ 1024
#define F_ 4096
#define H_ 16
#define DH_ 64
#define L_ 6
#define M_ (B_*S_)

typedef unsigned short u16;
typedef __attribute__((ext_vector_type(4))) unsigned short u16x4;
typedef __attribute__((ext_vector_type(8))) short s16x8;
typedef __attribute__((ext_vector_type(8))) __bf16 bf16x8;
typedef __attribute__((ext_vector_type(4))) float f32x4;

__device__ __forceinline__ u16 f2bf(float f) {
  union { float f; unsigned u; } v; v.f = f;
  unsigned u = v.u;
  return (u16)((u + 0x7fffu + ((u >> 16) & 1u)) >> 16);  // RNE
}

__device__ __forceinline__ f32x4 mfma16(s16x8 a, s16x8 b, f32x4 c) {
  return __builtin_amdgcn_mfma_f32_16x16x32_bf16(
      __builtin_bit_cast(bf16x8, a), __builtin_bit_cast(bf16x8, b), c, 0, 0, 0);
}

// ---------------- weight transpose + fp32->bf16: src[R][C] -> dst[C][R] ----
__global__ __launch_bounds__(256) void transpose_cvt(
    const float* __restrict__ src, u16* __restrict__ dst, int R, int Cc)
{
  __shared__ float t[32][33];
  const int c0 = blockIdx.x * 32, r0 = blockIdx.y * 32;
  const int tx = threadIdx.x & 31, ty = threadIdx.x >> 5;  // ty 0..7
#pragma unroll
  for (int i = 0; i < 4; i++)
    t[ty + 8 * i][tx] = src[(size_t)(r0 + ty + 8 * i) * Cc + c0 + tx];
  __syncthreads();
#pragma unroll
  for (int i = 0; i < 4; i++)
    dst[(size_t)(c0 + ty + 8 * i) * R + r0 + tx] = f2bf(t[tx][ty + 8 * i]);
}

// ---------------- GEMM: C[M,N] = A[M,K](f32) @ Bt[N,K](bf16)^T + bias ------
#define LDK 72  // padded LDS stride (bf16 elems): 64 + 8 keeps 16B align, kills bank conflicts

__device__ __forceinline__ void gemm_body(
    const float* __restrict__ A, const u16* __restrict__ Bt,
    const float* __restrict__ bias, float* __restrict__ C,
    int N, int K, int do_relu, int bm, int bn)
{
  __shared__ u16 As[128 * LDK];
  __shared__ u16 Bs[128 * LDK];
  const int tid = threadIdx.x;
  const int lane = tid & 63;
  const int wid = tid >> 6;
  const int wm = (wid >> 1) << 6;   // wave 64x64 sub-tile
  const int wn = (wid & 1) << 6;

  f32x4 acc[4][4];
#pragma unroll
  for (int i = 0; i < 4; i++)
#pragma unroll
    for (int j = 0; j < 4; j++)
      acc[i][j] = {0.f, 0.f, 0.f, 0.f};

  for (int k0 = 0; k0 < K; k0 += 64) {
    __syncthreads();
    // stage A 128x64 f32 -> bf16
#pragma unroll
    for (int i = 0; i < 8; i++) {
      int c = tid + i * 256;
      int row = c >> 4, c4 = c & 15;
      const float4 v = *(const float4*)(A + (size_t)(bm + row) * K + k0 + c4 * 4);
      u16x4 hv;
      hv.x = f2bf(v.x); hv.y = f2bf(v.y); hv.z = f2bf(v.z); hv.w = f2bf(v.w);
      *(u16x4*)(&As[row * LDK + c4 * 4]) = hv;
    }
    // stage B 128x64 bf16
#pragma unroll
    for (int i = 0; i < 4; i++) {
      int c = tid + i * 256;
      int row = c >> 3, ch = c & 7;
      s16x8 v = *(const s16x8*)(Bt + (size_t)(bn + row) * K + k0 + ch * 8);
      *(s16x8*)(&Bs[row * LDK + ch * 8]) = v;
    }
    __syncthreads();
#pragma unroll
    for (int kk = 0; kk < 2; kk++) {
      s16x8 af[4], bfr[4];
#pragma unroll
      for (int mf = 0; mf < 4; mf++)
        af[mf] = *(const s16x8*)(&As[(wm + mf * 16 + (lane & 15)) * LDK + kk * 32 + (lane >> 4) * 8]);
#pragma unroll
      for (int nf = 0; nf < 4; nf++)
        bfr[nf] = *(const s16x8*)(&Bs[(wn + nf * 16 + (lane & 15)) * LDK + kk * 32 + (lane >> 4) * 8]);
#pragma unroll
      for (int mf = 0; mf < 4; mf++)
#pragma unroll
        for (int nf = 0; nf < 4; nf++)
          acc[mf][nf] = mfma16(af[mf], bfr[nf], acc[mf][nf]);
    }
  }
  // epilogue: C layout row=(lane>>4)*4+j, col=lane&15
#pragma unroll
  for (int nf = 0; nf < 4; nf++) {
    const int col = bn + wn + nf * 16 + (lane & 15);
    const float bv = bias[col];
#pragma unroll
    for (int mf = 0; mf < 4; mf++) {
#pragma unroll
      for (int j = 0; j < 4; j++) {
        float v = acc[mf][nf][j] + bv;
        if (do_relu) v = fmaxf(v, 0.f);
        const int row = bm + wm + mf * 16 + ((lane >> 4) << 2) + j;
        C[(size_t)row * N + col] = v;
      }
    }
  }
}

__global__ __launch_bounds__(256, 2) void gemm_one(
    const float* __restrict__ A, const u16* __restrict__ Bt,
    const float* __restrict__ bias, float* __restrict__ C,
    int N, int K, int do_relu)
{
  gemm_body(A, Bt, bias, C, N, K, do_relu, blockIdx.x * 128, blockIdx.y * 128);
}

// QKV fused over blockIdx.z for occupancy (3x256 blocks in one launch)
__global__ __launch_bounds__(256, 2) void gemm_qkv(
    const float* __restrict__ A, const u16* __restrict__ WT,
    const float* __restrict__ bq, const float* __restrict__ bk,
    const float* __restrict__ bv, float* __restrict__ Cb)
{
  const int z = blockIdx.z;
  const u16* Bt = WT + (size_t)z * D_ * D_;
  const float* bias = (z == 0) ? bq : ((z == 1) ? bk : bv);
  float* C = Cb + (size_t)z * M_ * D_;
  gemm_body(A, Bt, bias, C, D_, D_, 0, blockIdx.x * 128, blockIdx.y * 128);
}

// ---------------- fused flash attention with T5 rel-bias -------------------
__global__ __launch_bounds__(256, 2) void attn_kernel(
    const float* __restrict__ Q, const float* __restrict__ K,
    const float* __restrict__ V, const int* __restrict__ mask,
    const float* __restrict__ rb,   // this layer's rel_bias [32][16]
    float* __restrict__ O)
{
  __shared__ float lut[2048];
  __shared__ u16 Ks[64 * LDK];
  __shared__ u16 Vt[64 * LDK];        // transposed: [dh][k]
  __shared__ u16 Ps[4][32 * LDK];     // per-wave P tile

  const int tid = threadIdx.x;
  const int lane = tid & 63;
  const int w = tid >> 6;
  const int b = blockIdx.x >> 4;
  const int h = blockIdx.x & 15;
  const int q0 = blockIdx.y * 128 + w * 32;

  // bias LUT over rel = q-k in [-1024, 1023]; mirrors reference f32 math
  for (int idx = tid; idx < 2048; idx += 256) {
    int rel = idx - 1024;
    int ret = rel < 0 ? 16 : 0;
    int n = rel < 0 ? -rel : rel;
    int bu;
    if (n < 8) bu = ret + n;
    else {
      float t = logf((float)n * 0.125f) / 3.4657359027997265f * 8.0f;
      int vl = 8 + (int)t;
      if (vl > 15) vl = 15;
      bu = ret + vl;
    }
    lut[idx] = rb[bu * 16 + h] * 8.0f;   // REL_SCALE = sqrt(64)
  }

  // Q fragments, pre-scaled by 1/sqrt(DH)=0.125
  s16x8 qf[2][2];
#pragma unroll
  for (int mf = 0; mf < 2; mf++)
#pragma unroll
    for (int kk = 0; kk < 2; kk++) {
      const int row = q0 + mf * 16 + (lane & 15);
      const int kcol = kk * 32 + (lane >> 4) * 8;
      const float* p = Q + (size_t)(b * S_ + row) * D_ + h * DH_ + kcol;
      const float4 v0 = *(const float4*)p;
      const float4 v1 = *(const float4*)(p + 4);
      s16x8 q8;
      q8[0] = (short)f2bf(v0.x * 0.125f); q8[1] = (short)f2bf(v0.y * 0.125f);
      q8[2] = (short)f2bf(v0.z * 0.125f); q8[3] = (short)f2bf(v0.w * 0.125f);
      q8[4] = (short)f2bf(v1.x * 0.125f); q8[5] = (short)f2bf(v1.y * 0.125f);
      q8[6] = (short)f2bf(v1.z * 0.125f); q8[7] = (short)f2bf(v1.w * 0.125f);
      qf[mf][kk] = q8;
    }

  f32x4 oacc[2][4];
#pragma unroll
  for (int i = 0; i < 2; i++)
#pragma unroll
    for (int j = 0; j < 4; j++) oacc[i][j] = {0.f, 0.f, 0.f, 0.f};
  float rm[2][4], rl[2][4];
#pragma unroll
  for (int i = 0; i < 2; i++)
#pragma unroll
    for (int j = 0; j < 4; j++) { rm[i][j] = -3e38f; rl[i][j] = 0.f; }

  for (int kt = 0; kt < S_; kt += 64) {
    __syncthreads();
    // stage K[64][64] and V^T[64][64]
#pragma unroll
    for (int i = 0; i < 4; i++) {
      int c = tid + i * 256;
      int row = c >> 4, c4 = c & 15;
      const size_t gbase = (size_t)(b * S_ + kt + row) * D_ + h * DH_ + c4 * 4;
      const float4 kv = *(const float4*)(K + gbase);
      u16x4 hk;
      hk.x = f2bf(kv.x); hk.y = f2bf(kv.y); hk.z = f2bf(kv.z); hk.w = f2bf(kv.w);
      *(u16x4*)(&Ks[row * LDK + c4 * 4]) = hk;
      const float4 vv = *(const float4*)(V + gbase);
      Vt[(c4 * 4 + 0) * LDK + row] = f2bf(vv.x);
      Vt[(c4 * 4 + 1) * LDK + row] = f2bf(vv.y);
      Vt[(c4 * 4 + 2) * LDK + row] = f2bf(vv.z);
      Vt[(c4 * 4 + 3) * LDK + row] = f2bf(vv.w);
    }
    __syncthreads();

    // S = Q K^T (already scaled)
    f32x4 sacc[2][4];
#pragma unroll
    for (int i = 0; i < 2; i++)
#pragma unroll
      for (int j = 0; j < 4; j++) sacc[i][j] = {0.f, 0.f, 0.f, 0.f};
#pragma unroll
    for (int kk = 0; kk < 2; kk++) {
      s16x8 kb[4];
#pragma unroll
      for (int nf = 0; nf < 4; nf++)
        kb[nf] = *(const s16x8*)(&Ks[(nf * 16 + (lane & 15)) * LDK + kk * 32 + (lane >> 4) * 8]);
#pragma unroll
      for (int mf = 0; mf < 2; mf++)
#pragma unroll
        for (int nf = 0; nf < 4; nf++)
          sacc[mf][nf] = mfma16(qf[mf][kk], kb[nf], sacc[mf][nf]);
    }

    // mask per key (hoisted)
    int km[4];
#pragma unroll
    for (int nf = 0; nf < 4; nf++)
      km[nf] = mask[(size_t)b * S_ + kt + nf * 16 + (lane & 15)];

    // online softmax
#pragma unroll
    for (int mf = 0; mf < 2; mf++) {
#pragma unroll
      for (int j = 0; j < 4; j++) {
        const int lrow = mf * 16 + ((lane >> 4) << 2) + j;
        const int qrow = q0 + lrow;
        float sc[4];
        float mx = -3e38f;
#pragma unroll
        for (int nf = 0; nf < 4; nf++) {
          const int key = kt + nf * 16 + (lane & 15);
          float s = sacc[mf][nf][j];
          if (km[nf] == 0) s = -1e10f;
          s += lut[qrow - key + 1024];
          sc[nf] = s;
          mx = fmaxf(mx, s);
        }
        mx = fmaxf(mx, __shfl_xor(mx, 1));
        mx = fmaxf(mx, __shfl_xor(mx, 2));
        mx = fmaxf(mx, __shfl_xor(mx, 4));
        mx = fmaxf(mx, __shfl_xor(mx, 8));
        const float m_new = fmaxf(rm[mf][j], mx);
        const float fs = expf(rm[mf][j] - m_new);
        rm[mf][j] = m_new;
        float psum = 0.f;
#pragma unroll
        for (int nf = 0; nf < 4; nf++) {
          const float p = expf(sc[nf] - m_new);
          psum += p;
          Ps[w][lrow * LDK + nf * 16 + (lane & 15)] = f2bf(p);
        }
        psum += __shfl_xor(psum, 1);
        psum += __shfl_xor(psum, 2);
        psum += __shfl_xor(psum, 4);
        psum += __shfl_xor(psum, 8);
        rl[mf][j] = rl[mf][j] * fs + psum;
#pragma unroll
        for (int df = 0; df < 4; df++) oacc[mf][df][j] *= fs;
      }
    }

    // O += P @ V
#pragma unroll
    for (int kk = 0; kk < 2; kk++) {
      s16x8 pa[2], vb[4];
#pragma unroll
      for (int mf = 0; mf < 2; mf++)
        pa[mf] = *(const s16x8*)(&Ps[w][(mf * 16 + (lane & 15)) * LDK + kk * 32 + (lane >> 4) * 8]);
#pragma unroll
      for (int df = 0; df < 4; df++)
        vb[df] = *(const s16x8*)(&Vt[(df * 16 + (lane & 15)) * LDK + kk * 32 + (lane >> 4) * 8]);
#pragma unroll
      for (int mf = 0; mf < 2; mf++)
#pragma unroll
        for (int df = 0; df < 4; df++)
          oacc[mf][df] = mfma16(pa[mf], vb[df], oacc[mf][df]);
    }
  }

  // write O
#pragma unroll
  for (int mf = 0; mf < 2; mf++)
#pragma unroll
    for (int df = 0; df < 4; df++)
#pragma unroll
      for (int j = 0; j < 4; j++) {
        const int qrow = q0 + mf * 16 + ((lane >> 4) << 2) + j;
        const int dh = df * 16 + (lane & 15);
        O[(size_t)(b * S_ + qrow) * D_ + h * DH_ + dh] = oacc[mf][df][j] / rl[mf][j];
      }
}

// ---------------- residual + LayerNorm -------------------------------------
__global__ __launch_bounds__(256) void ln_kernel(
    const float* X, const float* R, const float* g, const float* be, float* Y)
{
  const int row = blockIdx.x;
  const int tid = threadIdx.x;
  const float4 xv = ((const float4*)(X + (size_t)row * D_))[tid];
  const float4 rv = ((const float4*)(R + (size_t)row * D_))[tid];
  float v0 = xv.x + rv.x, v1 = xv.y + rv.y, v2 = xv.z + rv.z, v3 = xv.w + rv.w;
  float sum = v0 + v1 + v2 + v3;
  float ss = v0 * v0 + v1 * v1 + v2 * v2 + v3 * v3;
#pragma unroll
  for (int o = 1; o < 64; o <<= 1) {
    sum += __shfl_xor(sum, o);
    ss += __shfl_xor(ss, o);
  }
  __shared__ float s1[4], s2[4];
  if ((tid & 63) == 0) { s1[tid >> 6] = sum; s2[tid >> 6] = ss; }
  __syncthreads();
  sum = s1[0] + s1[1] + s1[2] + s1[3];
  ss = s2[0] + s2[1] + s2[2] + s2[3];
  const float mu = sum * (1.f / D_);
  const float var = ss * (1.f / D_) - mu * mu;
  const float rstd = rsqrtf(var + 1e-5f);
  const float4 gv = ((const float4*)g)[tid];
  const float4 bv = ((const float4*)be)[tid];
  float4 y;
  y.x = (v0 - mu) * rstd * gv.x + bv.x;
  y.y = (v1 - mu) * rstd * gv.y + bv.y;
  y.z = (v2 - mu) * rstd * gv.z + bv.z;
  y.w = (v3 - mu) * rstd * gv.w + bv.w;
  ((float4*)(Y + (size_t)row * D_))[tid] = y;
}

// ---------------- embedding ------------------------------------------------
__global__ __launch_bounds__(256) void embed_kernel(
    const int* __restrict__ src, const float* __restrict__ tok,
    const float* __restrict__ pos, float* __restrict__ X)
{
  const int row = blockIdx.x;
  const int s = row & (S_ - 1);
  const int t = src[row];
  const int tid = threadIdx.x;
  const float4 tv = ((const float4*)(tok + (size_t)t * D_))[tid];
  const float4 pv = ((const float4*)(pos + (size_t)s * D_))[tid];
  float4 y;
  y.x = tv.x * 32.f + pv.x;
  y.y = tv.y * 32.f + pv.y;
  y.z = tv.z * 32.f + pv.z;
  y.w = tv.w * 32.f + pv.w;
  ((float4*)(X + (size_t)row * D_))[tid] = y;
}

// ---------------- launch ----------------------------------------------------
extern "C" void kernel_launch(void* const* d_in, const int* in_sizes, int n_in,
                              void* d_out, int out_size, void* d_ws, size_t ws_size,
                              hipStream_t stream)
{
  const int* src = (const int*)d_in[0];
  const int* mask = (const int*)d_in[1];
  const float* tok_emb = (const float*)d_in[2];
  const float* pos_emb = (const float*)d_in[3];
  const float* Wq = (const float*)d_in[4];
  const float* bq = (const float*)d_in[5];
  const float* Wk = (const float*)d_in[6];
  const float* bk = (const float*)d_in[7];
  const float* Wv = (const float*)d_in[8];
  const float* bv = (const float*)d_in[9];
  const float* Wo = (const float*)d_in[10];
  const float* bo = (const float*)d_in[11];
  const float* rb = (const float*)d_in[12];
  const float* g1 = (const float*)d_in[13];
  const float* b1n = (const float*)d_in[14];
  const float* W1 = (const float*)d_in[15];
  const float* b1f = (const float*)d_in[16];
  const float* W2 = (const float*)d_in[17];
  const float* b2f = (const float*)d_in[18];
  const float* g2 = (const float*)d_in[19];
  const float* b2n = (const float*)d_in[20];
  float* out = (float*)d_out;

  // ws map (120MB):
  //  0-16M   xb
  // 16-32M   Qb  (reused as OP after attn, then Fb after LN1)
  // 32-48M   Kb  \
  // 48-64M   Vb   } reused as Hb (64MB @32M) after o-proj
  // 64-80M   AO  /
  // 96-102M  WTqkv (3 x 2MB bf16)
  // 102-104M WTo
  // 104-112M WT1
  // 112-120M WT2
  char* ws = (char*)d_ws;
  const size_t MB = 1ull << 20;
  float* xb = (float*)(ws + 0);
  float* Qb = (float*)(ws + 16 * MB);
  float* Kb = (float*)(ws + 32 * MB);
  float* Vb = (float*)(ws + 48 * MB);
  float* AO = (float*)(ws + 64 * MB);
  float* OP = Qb;
  float* Hb = (float*)(ws + 32 * MB);
  float* Fb = Qb;
  u16* WTqkv = (u16*)(ws + 96 * MB);
  u16* WTo = (u16*)(ws + 102 * MB);
  u16* WT1 = (u16*)(ws + 104 * MB);
  u16* WT2 = (u16*)(ws + 112 * MB);

  embed_kernel<<<M_, 256, 0, stream>>>(src, tok_emb, pos_emb, xb);

  for (int l = 0; l < L_; l++) {
    const size_t oDD = (size_t)l * D_ * D_;
    const size_t oDF = (size_t)l * D_ * F_;
    transpose_cvt<<<dim3(D_ / 32, D_ / 32), 256, 0, stream>>>(Wq + oDD, WTqkv, D_, D_);
    transpose_cvt<<<dim3(D_ / 32, D_ / 32), 256, 0, stream>>>(Wk + oDD, WTqkv + (size_t)D_ * D_, D_, D_);
    transpose_cvt<<<dim3(D_ / 32, D_ / 32), 256, 0, stream>>>(Wv + oDD, WTqkv + 2 * (size_t)D_ * D_, D_, D_);
    transpose_cvt<<<dim3(D_ / 32, D_ / 32), 256, 0, stream>>>(Wo + oDD, WTo, D_, D_);
    transpose_cvt<<<dim3(F_ / 32, D_ / 32), 256, 0, stream>>>(W1 + oDF, WT1, D_, F_);
    transpose_cvt<<<dim3(D_ / 32, F_ / 32), 256, 0, stream>>>(W2 + oDF, WT2, F_, D_);

    gemm_qkv<<<dim3(M_ / 128, D_ / 128, 3), 256, 0, stream>>>(
        xb, WTqkv, bq + l * D_, bk + l * D_, bv + l * D_, Qb);

    attn_kernel<<<dim3(B_ * H_, S_ / 128), 256, 0, stream>>>(
        Qb, Kb, Vb, mask, rb + l * 32 * H_, AO);

    gemm_one<<<dim3(M_ / 128, D_ / 128), 256, 0, stream>>>(
        AO, WTo, bo + l * D_, OP, D_, D_, 0);

    ln_kernel<<<M_, 256, 0, stream>>>(xb, OP, g1 + l * D_, b1n + l * D_, xb);

    gemm_one<<<dim3(M_ / 128, F_ / 128), 256, 0, stream>>>(
        xb, WT1, b1f + l * F_, Hb, F_, D_, 1);

    gemm_one<<<dim3(M_ / 128, D_ / 128), 256, 0, stream>>>(
        Hb, WT2, b2f + l * D_, Fb, D_, F_, 0);

    ln_kernel<<<M_, 256, 0, stream>>>(xb, Fb, g2 + l * D_, b2n + l * D_,
                                      (l == L_ - 1) ? out : xb);
  }
}

// Round 2
// 1511.280 us; speedup vs baseline: 1.4806x; 1.4806x over previous
//
#include <hip/hip_runtime.h>

#define B_ 4
#define S_ 1024
#define D_ 1024
#define F_ 4096
#define H_ 16
#define L_ 6
#define M_ (B_*S_)

typedef unsigned short u16;
typedef __attribute__((ext_vector_type(4))) unsigned short u16x4;
typedef __attribute__((ext_vector_type(8))) short s16x8;
typedef __attribute__((ext_vector_type(8))) __bf16 bf16x8;
typedef __attribute__((ext_vector_type(4))) float f32x4;

typedef const __attribute__((address_space(1))) unsigned int gu32;
typedef __attribute__((address_space(3))) unsigned int su32;

__device__ __forceinline__ u16 f2bf(float f) {
  union { float f; unsigned u; } v; v.f = f;
  unsigned u = v.u;
  return (u16)((u + 0x7fffu + ((u >> 16) & 1u)) >> 16);  // RNE
}

__device__ __forceinline__ f32x4 mfma16(s16x8 a, s16x8 b, f32x4 c) {
  return __builtin_amdgcn_mfma_f32_16x16x32_bf16(
      __builtin_bit_cast(bf16x8, a), __builtin_bit_cast(bf16x8, b), c, 0, 0, 0);
}

__device__ __forceinline__ void gload16(const void* g, void* s) {
  __builtin_amdgcn_global_load_lds((gu32*)g, (su32*)s, 16, 0, 0);
}

// swizzled LDS read: tile rows of 128B, byte ^= (row&7)<<4
__device__ __forceinline__ s16x8 lds_swz(const u16* base, int row, int cb) {
  const int addr = row * 128 + (cb ^ ((row & 7) << 4));
  return *(const s16x8*)((const char*)base + addr);
}

// ---------------- weight transposes (f32 [R][C] -> bf16 [C][R]) ------------
__global__ __launch_bounds__(256) void transpose_cvt(
    const float* __restrict__ src, u16* __restrict__ dst, int R, int Cc)
{
  __shared__ float t[32][33];
  const int c0 = blockIdx.x * 32, r0 = blockIdx.y * 32;
  const int tx = threadIdx.x & 31, ty = threadIdx.x >> 5;
#pragma unroll
  for (int i = 0; i < 4; i++)
    t[ty + 8 * i][tx] = src[(size_t)(r0 + ty + 8 * i) * Cc + c0 + tx];
  __syncthreads();
#pragma unroll
  for (int i = 0; i < 4; i++)
    dst[(size_t)(c0 + ty + 8 * i) * R + r0 + tx] = f2bf(t[tx][ty + 8 * i]);
}

__global__ __launch_bounds__(256) void transpose4(
    const float* __restrict__ Wq, const float* __restrict__ Wk,
    const float* __restrict__ Wv, const float* __restrict__ Wo,
    u16* __restrict__ WTqkv, u16* __restrict__ WTo)
{
  __shared__ float t[32][33];
  const int z = blockIdx.z;
  const float* src = (z == 0) ? Wq : (z == 1) ? Wk : (z == 2) ? Wv : Wo;
  u16* dst = (z < 3) ? WTqkv + (size_t)z * D_ * D_ : WTo;
  const int c0 = blockIdx.x * 32, r0 = blockIdx.y * 32;
  const int tx = threadIdx.x & 31, ty = threadIdx.x >> 5;
#pragma unroll
  for (int i = 0; i < 4; i++)
    t[ty + 8 * i][tx] = src[(size_t)(r0 + ty + 8 * i) * D_ + c0 + tx];
  __syncthreads();
#pragma unroll
  for (int i = 0; i < 4; i++)
    dst[(size_t)(c0 + ty + 8 * i) * D_ + r0 + tx] = f2bf(t[tx][ty + 8 * i]);
}

// ---------------- GEMM (m97 structure): 128x128 tile, BK=64 ----------------
// OUTMODE 0: f32 partial (no bias)   1: bf16 (acc+bias)*scale   2: bf16 relu
template<int OUTMODE>
__device__ __forceinline__ void gemm128_body(
    const u16* __restrict__ A, const u16* __restrict__ Bt,
    const float* __restrict__ bias, float* __restrict__ Cf,
    u16* __restrict__ Ch, int N, int K, int kbeg, int kend, float scale)
{
  __shared__ __align__(16) u16 As[128 * 64];
  __shared__ __align__(16) u16 Bs[128 * 64];
  const int tid = threadIdx.x, lane = tid & 63, w = tid >> 6;
  const int bm = blockIdx.x * 128, bn = blockIdx.y * 128;
  const int wm = (w >> 1) * 64, wn = (w & 1) * 64;

  f32x4 acc[4][4];
#pragma unroll
  for (int i = 0; i < 4; i++)
#pragma unroll
    for (int j = 0; j < 4; j++) acc[i][j] = {0.f, 0.f, 0.f, 0.f};

  for (int k0 = kbeg; k0 < kend; k0 += 64) {
    __syncthreads();
#pragma unroll
    for (int i = 0; i < 4; i++) {
      const int flat = i * 4096 + w * 1024 + lane * 16;  // bytes in tile
      const int row = flat >> 7, ce = (flat & 127) >> 1;
      gload16(A + (size_t)(bm + row) * K + k0 + ce, As + i * 2048 + w * 512);
      gload16(Bt + (size_t)(bn + row) * K + k0 + ce, Bs + i * 2048 + w * 512);
    }
    __syncthreads();
#pragma unroll
    for (int kk = 0; kk < 2; kk++) {
      s16x8 af[4], bf[4];
#pragma unroll
      for (int mf = 0; mf < 4; mf++)
        af[mf] = *(const s16x8*)&As[(wm + mf * 16 + (lane & 15)) * 64 + kk * 32 + (lane >> 4) * 8];
#pragma unroll
      for (int nf = 0; nf < 4; nf++)
        bf[nf] = *(const s16x8*)&Bs[(wn + nf * 16 + (lane & 15)) * 64 + kk * 32 + (lane >> 4) * 8];
#pragma unroll
      for (int mf = 0; mf < 4; mf++)
#pragma unroll
        for (int nf = 0; nf < 4; nf++)
          acc[mf][nf] = mfma16(af[mf], bf[nf], acc[mf][nf]);
    }
  }
#pragma unroll
  for (int nf = 0; nf < 4; nf++) {
    const int col = bn + wn + nf * 16 + (lane & 15);
    const float bv = (OUTMODE == 0) ? 0.f : bias[col];
#pragma unroll
    for (int mf = 0; mf < 4; mf++) {
#pragma unroll
      for (int j = 0; j < 4; j++) {
        const int row = bm + wm + mf * 16 + ((lane >> 4) << 2) + j;
        float v = acc[mf][nf][j];
        if (OUTMODE == 0) {
          Cf[(size_t)row * N + col] = v;
        } else {
          v = (v + bv) * scale;
          if (OUTMODE == 2) v = fmaxf(v, 0.f);
          Ch[(size_t)row * N + col] = f2bf(v);
        }
      }
    }
  }
}

__global__ __launch_bounds__(256, 3) void gemm_qkv(
    const u16* __restrict__ A, const u16* __restrict__ WT,
    const float* __restrict__ bq, const float* __restrict__ bk,
    const float* __restrict__ bv, u16* __restrict__ Out)
{
  const int z = blockIdx.z;
  const float* bias = (z == 0) ? bq : (z == 1) ? bk : bv;
  gemm128_body<1>(A, WT + (size_t)z * D_ * D_, bias, nullptr,
                  Out + (size_t)z * M_ * D_, D_, D_, 0, D_,
                  (z == 0) ? 0.125f : 1.0f);
}

__global__ __launch_bounds__(256, 3) void gemm_ffn1(
    const u16* __restrict__ A, const u16* __restrict__ WT,
    const float* __restrict__ bias, u16* __restrict__ Out)
{
  gemm128_body<2>(A, WT, bias, nullptr, Out, F_, D_, 0, D_, 1.0f);
}

__global__ __launch_bounds__(256, 3) void gemm_splitk(
    const u16* __restrict__ A, const u16* __restrict__ WT,
    float* __restrict__ P, int N, int K)
{
  const int z = blockIdx.z;
  const int half = K >> 1;
  gemm128_body<0>(A, WT, nullptr, P + (size_t)z * M_ * (size_t)N, nullptr,
                  N, K, z * half, z * half + half, 1.0f);
}

// ---------------- V^T pre-pass: Vb16[b*S+s][h*64+dh] -> Vt[(bh)*64+dh][s] --
__global__ __launch_bounds__(256) void vt_transpose(
    const u16* __restrict__ Vb, u16* __restrict__ Vt)
{
  __shared__ u16 t[64][66];
  const int s0 = blockIdx.x * 64;
  const int bh = blockIdx.y;
  const int b = bh >> 4, h = bh & 15;
  const int tid = threadIdx.x;
  const int row = tid >> 2;           // 0..63
  const int c0 = (tid & 3) * 16;      // 0..48
  const u16* src = Vb + (size_t)(b * S_ + s0 + row) * D_ + h * 64 + c0;
  *(s16x8*)&t[row][c0] = *(const s16x8*)src;
  *(s16x8*)&t[row][c0 + 8] = *(const s16x8*)(src + 8);
  __syncthreads();
  const int dh = tid >> 2;
  const int sc = (tid & 3) * 16;
  s16x8 a, bv;
#pragma unroll
  for (int u = 0; u < 8; u++) a[u] = (short)t[sc + u][dh];
#pragma unroll
  for (int u = 0; u < 8; u++) bv[u] = (short)t[sc + 8 + u][dh];
  u16* dst = Vt + (size_t)(bh * 64 + dh) * S_ + s0 + sc;
  *(s16x8*)dst = a;
  *(s16x8*)(dst + 8) = bv;
}

// ---------------- flash attention, 64 q-rows/block, swizzled K/V tiles -----
__global__ __launch_bounds__(256, 4) void attn_kernel(
    const u16* __restrict__ Qb, const u16* __restrict__ Kb,
    const u16* __restrict__ Vt, const int* __restrict__ mask,
    const float* __restrict__ rb, u16* __restrict__ AO)
{
  __shared__ float lut[2048];
  __shared__ __align__(16) u16 Ks[64 * 64];
  __shared__ __align__(16) u16 Vs[64 * 64];
  __shared__ __align__(16) u16 Ps[4][16 * 68];

  const int tid = threadIdx.x;
  const int lane = tid & 63;
  const int w = tid >> 6;
  const int bh = blockIdx.x;
  const int b = bh >> 4, h = bh & 15;
  const int q0 = blockIdx.y * 64 + w * 16;
  const int bS = b * S_, hh = h * 64;

  for (int idx = tid; idx < 2048; idx += 256) {
    const int rel = idx - 1024;
    const int ret = rel < 0 ? 16 : 0;
    const int n = rel < 0 ? -rel : rel;
    int bu;
    if (n < 8) bu = ret + n;
    else {
      const float t = logf((float)n * 0.125f) * (8.0f / 3.4657359027997265f);
      int vl = 8 + (int)t;
      if (vl > 15) vl = 15;
      bu = ret + vl;
    }
    lut[idx] = rb[bu * 16 + h] * 8.0f;
  }

  // Q fragments (Q pre-scaled by 0.125 in the QKV GEMM epilogue)
  s16x8 qf[2];
#pragma unroll
  for (int kk = 0; kk < 2; kk++)
    qf[kk] = *(const s16x8*)(Qb + (size_t)(bS + q0 + (lane & 15)) * D_ + hh +
                             kk * 32 + (lane >> 4) * 8);

  f32x4 oacc[4];
#pragma unroll
  for (int i = 0; i < 4; i++) oacc[i] = {0.f, 0.f, 0.f, 0.f};
  float rm[4], rl[4];
#pragma unroll
  for (int j = 0; j < 4; j++) { rm[j] = -3e38f; rl[j] = 0.f; }

  for (int kt = 0; kt < S_; kt += 64) {
    __syncthreads();
    // stage K (rows=key) and V^T (rows=dh) with inverse-swizzled source
#pragma unroll
    for (int i = 0; i < 2; i++) {
      const int flat = i * 4096 + w * 1024 + lane * 16;
      const int row = flat >> 7;
      const int ce = ((flat & 127) ^ ((row & 7) << 4)) >> 1;
      gload16(Kb + (size_t)(bS + kt + row) * D_ + hh + ce, Ks + i * 2048 + w * 512);
      gload16(Vt + (size_t)(bh * 64 + row) * S_ + kt + ce, Vs + i * 2048 + w * 512);
    }
    __syncthreads();

    // S = Q K^T
    f32x4 sacc[4];
#pragma unroll
    for (int i = 0; i < 4; i++) sacc[i] = {0.f, 0.f, 0.f, 0.f};
#pragma unroll
    for (int kk = 0; kk < 2; kk++) {
      const int cb = kk * 64 + (lane >> 4) * 16;
#pragma unroll
      for (int nf = 0; nf < 4; nf++) {
        const s16x8 kb = lds_swz(Ks, nf * 16 + (lane & 15), cb);
        sacc[nf] = mfma16(qf[kk], kb, sacc[nf]);
      }
    }

    int km[4];
#pragma unroll
    for (int nf = 0; nf < 4; nf++)
      km[nf] = mask[bS + kt + nf * 16 + (lane & 15)];

    const int lidx0 = q0 + (lane >> 4) * 4 + 1024 - kt - (lane & 15);
#pragma unroll
    for (int j = 0; j < 4; j++) {
      const int lrow = ((lane >> 4) << 2) + j;
      float sc[4];
      float mx = -3e38f;
#pragma unroll
      for (int nf = 0; nf < 4; nf++) {
        float s = (km[nf] == 0) ? -1e10f : sacc[nf][j];
        s += lut[lidx0 + j - nf * 16];
        sc[nf] = s;
        mx = fmaxf(mx, s);
      }
      mx = fmaxf(mx, __shfl_xor(mx, 1));
      mx = fmaxf(mx, __shfl_xor(mx, 2));
      mx = fmaxf(mx, __shfl_xor(mx, 4));
      mx = fmaxf(mx, __shfl_xor(mx, 8));
      const float m_new = fmaxf(rm[j], mx);
      const float fs = __expf(rm[j] - m_new);
      rm[j] = m_new;
      float psum = 0.f;
#pragma unroll
      for (int nf = 0; nf < 4; nf++) {
        const float p = __expf(sc[nf] - m_new);
        psum += p;
        Ps[w][lrow * 68 + nf * 16 + (lane & 15)] = f2bf(p);
      }
      psum += __shfl_xor(psum, 1);
      psum += __shfl_xor(psum, 2);
      psum += __shfl_xor(psum, 4);
      psum += __shfl_xor(psum, 8);
      rl[j] = rl[j] * fs + psum;
#pragma unroll
      for (int df = 0; df < 4; df++) oacc[df][j] *= fs;
    }

    // O += P V
#pragma unroll
    for (int kk = 0; kk < 2; kk++) {
      const s16x8 pa = *(const s16x8*)&Ps[w][(lane & 15) * 68 + kk * 32 + (lane >> 4) * 8];
      const int cb = kk * 64 + (lane >> 4) * 16;
#pragma unroll
      for (int df = 0; df < 4; df++) {
        const s16x8 vb = lds_swz(Vs, df * 16 + (lane & 15), cb);
        oacc[df] = mfma16(pa, vb, oacc[df]);
      }
    }
  }

  float inv[4];
#pragma unroll
  for (int j = 0; j < 4; j++) inv[j] = 1.0f / rl[j];
#pragma unroll
  for (int df = 0; df < 4; df++)
#pragma unroll
    for (int j = 0; j < 4; j++) {
      const int qrow = q0 + ((lane >> 4) << 2) + j;
      AO[(size_t)(bS + qrow) * D_ + hh + df * 16 + (lane & 15)] =
          f2bf(oacc[df][j] * inv[j]);
    }
}

// ---------------- fused: Y = LN(X + P0 + P1 + bias) ------------------------
__global__ __launch_bounds__(256) void ln_fused(
    const float* __restrict__ X, const float* __restrict__ P0,
    const float* __restrict__ P1, const float* __restrict__ bias,
    const float* __restrict__ g, const float* __restrict__ be,
    float* __restrict__ Yf, u16* __restrict__ Yh)
{
  const int row = blockIdx.x;
  const int tid = threadIdx.x;
  const float4 xv = ((const float4*)(X + (size_t)row * D_))[tid];
  const float4 p0 = ((const float4*)(P0 + (size_t)row * D_))[tid];
  const float4 p1 = ((const float4*)(P1 + (size_t)row * D_))[tid];
  const float4 bb = ((const float4*)bias)[tid];
  const float v0 = xv.x + p0.x + p1.x + bb.x;
  const float v1 = xv.y + p0.y + p1.y + bb.y;
  const float v2 = xv.z + p0.z + p1.z + bb.z;
  const float v3 = xv.w + p0.w + p1.w + bb.w;
  float sum = v0 + v1 + v2 + v3;
  float ss = v0 * v0 + v1 * v1 + v2 * v2 + v3 * v3;
#pragma unroll
  for (int o = 1; o < 64; o <<= 1) {
    sum += __shfl_xor(sum, o);
    ss += __shfl_xor(ss, o);
  }
  __shared__ float s1[4], s2[4];
  if ((tid & 63) == 0) { s1[tid >> 6] = sum; s2[tid >> 6] = ss; }
  __syncthreads();
  sum = s1[0] + s1[1] + s1[2] + s1[3];
  ss = s2[0] + s2[1] + s2[2] + s2[3];
  const float mu = sum * (1.f / D_);
  const float var = ss * (1.f / D_) - mu * mu;
  const float rstd = rsqrtf(var + 1e-5f);
  const float4 gv = ((const float4*)g)[tid];
  const float4 bv = ((const float4*)be)[tid];
  float4 y;
  y.x = (v0 - mu) * rstd * gv.x + bv.x;
  y.y = (v1 - mu) * rstd * gv.y + bv.y;
  y.z = (v2 - mu) * rstd * gv.z + bv.z;
  y.w = (v3 - mu) * rstd * gv.w + bv.w;
  ((float4*)(Yf + (size_t)row * D_))[tid] = y;
  u16x4 hv;
  hv.x = f2bf(y.x); hv.y = f2bf(y.y); hv.z = f2bf(y.z); hv.w = f2bf(y.w);
  ((u16x4*)(Yh + (size_t)row * D_))[tid] = hv;
}

// ---------------- embedding -------------------------------------------------
__global__ __launch_bounds__(256) void embed_kernel(
    const int* __restrict__ src, const float* __restrict__ tok,
    const float* __restrict__ pos, float* __restrict__ X, u16* __restrict__ Xh)
{
  const int row = blockIdx.x;
  const int s = row & (S_ - 1);
  const int t = src[row];
  const int tid = threadIdx.x;
  const float4 tv = ((const float4*)(tok + (size_t)t * D_))[tid];
  const float4 pv = ((const float4*)(pos + (size_t)s * D_))[tid];
  float4 y;
  y.x = tv.x * 32.f + pv.x;
  y.y = tv.y * 32.f + pv.y;
  y.z = tv.z * 32.f + pv.z;
  y.w = tv.w * 32.f + pv.w;
  ((float4*)(X + (size_t)row * D_))[tid] = y;
  u16x4 hv;
  hv.x = f2bf(y.x); hv.y = f2bf(y.y); hv.z = f2bf(y.z); hv.w = f2bf(y.w);
  ((u16x4*)(Xh + (size_t)row * D_))[tid] = hv;
}

// ---------------- launch ----------------------------------------------------
extern "C" void kernel_launch(void* const* d_in, const int* in_sizes, int n_in,
                              void* d_out, int out_size, void* d_ws, size_t ws_size,
                              hipStream_t stream)
{
  const int* src = (const int*)d_in[0];
  const int* mask = (const int*)d_in[1];
  const float* tok_emb = (const float*)d_in[2];
  const float* pos_emb = (const float*)d_in[3];
  const float* Wq = (const float*)d_in[4];
  const float* bq = (const float*)d_in[5];
  const float* Wk = (const float*)d_in[6];
  const float* bk = (const float*)d_in[7];
  const float* Wv = (const float*)d_in[8];
  const float* bv = (const float*)d_in[9];
  const float* Wo = (const float*)d_in[10];
  const float* bo = (const float*)d_in[11];
  const float* rb = (const float*)d_in[12];
  const float* g1 = (const float*)d_in[13];
  const float* b1n = (const float*)d_in[14];
  const float* W1 = (const float*)d_in[15];
  const float* b1f = (const float*)d_in[16];
  const float* W2 = (const float*)d_in[17];
  const float* b2f = (const float*)d_in[18];
  const float* g2 = (const float*)d_in[19];
  const float* b2n = (const float*)d_in[20];
  float* out = (float*)d_out;

  // ws map (112 MB):
  //  0-16   xb f32
  // 16-24   xb16
  // 24-32   Qb16
  // 32-40   Kb16
  // 40-48   Vb16 -> (after vt) AO16
  // 48-56   Vt16
  // 48-80   OPp (2x16MB f32, after attn)
  // 24-56   Hb16 (after ln1)
  // 56-88   Fp  (2x16MB f32)
  // 88-112  WT: qkv(6) o(2) w1(8) w2(8)
  char* ws = (char*)d_ws;
  const size_t MB = 1ull << 20;
  float* xb   = (float*)(ws + 0);
  u16*   xb16 = (u16*)(ws + 16 * MB);
  u16*   Qb16 = (u16*)(ws + 24 * MB);
  u16*   Kb16 = (u16*)(ws + 32 * MB);
  u16*   Vb16 = (u16*)(ws + 40 * MB);
  u16*   Vt16 = (u16*)(ws + 48 * MB);
  u16*   AO16 = (u16*)(ws + 40 * MB);
  float* OPp  = (float*)(ws + 48 * MB);
  u16*   Hb16 = (u16*)(ws + 24 * MB);
  float* Fp   = (float*)(ws + 56 * MB);
  u16* WTqkv  = (u16*)(ws + 88 * MB);
  u16* WTo    = (u16*)(ws + 94 * MB);
  u16* WT1    = (u16*)(ws + 96 * MB);
  u16* WT2    = (u16*)(ws + 104 * MB);

  embed_kernel<<<M_, 256, 0, stream>>>(src, tok_emb, pos_emb, xb, xb16);

  for (int l = 0; l < L_; l++) {
    const size_t oDD = (size_t)l * D_ * D_;
    const size_t oDF = (size_t)l * D_ * F_;

    transpose4<<<dim3(32, 32, 4), 256, 0, stream>>>(
        Wq + oDD, Wk + oDD, Wv + oDD, Wo + oDD, WTqkv, WTo);
    transpose_cvt<<<dim3(F_ / 32, D_ / 32), 256, 0, stream>>>(W1 + oDF, WT1, D_, F_);
    transpose_cvt<<<dim3(D_ / 32, F_ / 32), 256, 0, stream>>>(W2 + oDF, WT2, F_, D_);

    gemm_qkv<<<dim3(M_ / 128, D_ / 128, 3), 256, 0, stream>>>(
        xb16, WTqkv, bq + l * D_, bk + l * D_, bv + l * D_, Qb16);

    vt_transpose<<<dim3(S_ / 64, B_ * H_), 256, 0, stream>>>(Vb16, Vt16);

    attn_kernel<<<dim3(B_ * H_, S_ / 64), 256, 0, stream>>>(
        Qb16, Kb16, Vt16, mask, rb + l * 32 * H_, AO16);

    gemm_splitk<<<dim3(M_ / 128, D_ / 128, 2), 256, 0, stream>>>(
        AO16, WTo, OPp, D_, D_);

    ln_fused<<<M_, 256, 0, stream>>>(
        xb, OPp, OPp + (size_t)M_ * D_, bo + l * D_,
        g1 + l * D_, b1n + l * D_, xb, xb16);

    gemm_ffn1<<<dim3(M_ / 128, F_ / 128), 256, 0, stream>>>(
        xb16, WT1, b1f + l * F_, Hb16);

    gemm_splitk<<<dim3(M_ / 128, D_ / 128, 2), 256, 0, stream>>>(
        Hb16, WT2, Fp, D_, F_);

    ln_fused<<<M_, 256, 0, stream>>>(
        xb, Fp, Fp + (size_t)M_ * D_, b2f + l * D_,
        g2 + l * D_, b2n + l * D_, (l == L_ - 1) ? out : xb, xb16);
  }
}